// Round 9
// baseline (41.450 us; speedup 1.0000x reference)
//
#include <hip/hip_runtime.h>

#define VOC 10000
#define NBLK 192

__device__ __forceinline__ float2 cmul(float2 a, float2 b) {
  return make_float2(a.x * b.x - a.y * b.y, a.x * b.y + a.y * b.x);
}
__device__ __forceinline__ float2 cmulj(float2 a, float2 b) { // a * conj(b)
  return make_float2(a.x * b.x + a.y * b.y, a.y * b.x - a.x * b.y);
}
__device__ __forceinline__ float2 cadd(float2 a, float2 b) {
  return make_float2(a.x + b.x, a.y + b.y);
}

// ws ints: [0]=c0 barrier ctr, [1]=c1 arrival ctr, [2..3] pad,
// [4..515] gram (2x256 f), [516..] part16 = u32[192][5000] (2 u16/word).
// memset node zeroes [0..515] (2064 B) every replay.
//
// Single kernel, 192 blocks (1 block/CU via launch_bounds => co-resident;
// validated by r5 coop + r7 spin).
//  P1: LDS hist of 4096 tokens; PLAIN coalesced u16-packed flush (the r7
//      per-word agent atomic-store flush was the ~19us cost — removed).
//      E-slice stage + rotm + CNOT tables hoisted here (overlap the spin).
//  B1: syncthreads; t0: threadfence + RELEASE atomicAdd(c0) + RELAXED polls
//      (no acquire-polling, no system-scope wbinv). Readers need no
//      invalidate: dispatch-start inv'd L2s; pre-barrier nobody read part16,
//      so reader L2s hold only their own dirty (correct) slices.
//  P2: 96+96 blocks, 106-row slices: packed count-sum + weighted-gram FMA
//      -> LLC atomicAdd into gram. M16 built by all blocks.
//  B2: vmcnt(0) + c1 arrival; 192nd block runs the verified tail inline.
// ---------------------------------------------------------------------------
__global__ __launch_bounds__(256, 1) void fused_kernel(
    const int* __restrict__ drug, const int* __restrict__ target,
    const float* __restrict__ Ed, const float* __restrict__ Et,
    const float* __restrict__ dw1, const float* __restrict__ db1,
    const float* __restrict__ tw1, const float* __restrict__ tb1,
    const float* __restrict__ dw2, const float* __restrict__ db2,
    const float* __restrict__ tw2, const float* __restrict__ tb2,
    const float* __restrict__ mw,
    const float* __restrict__ f1w, const float* __restrict__ f1b,
    const float* __restrict__ f2w, const float* __restrict__ f2b,
    float* __restrict__ out, int* __restrict__ ws) {

  __shared__ int h[VOC];            // 40 KB hist
  __shared__ float se[106 * 16];
  __shared__ float scnt[106];
  __shared__ int islast;
  // weights
  __shared__ float wconv[2][256];
  __shared__ float sw2[2][72];
  __shared__ float sb1[2][4], sb2[2][4];
  __shared__ float smw[48];
  __shared__ float sf1b[32], sf2w[32], sf2b[1];
  // tail scratch
  __shared__ float sgram[512];
  __shared__ float cmat[2][4][16];
  __shared__ float Hmat[2][16];
  __shared__ float ssum[2];
  __shared__ float2 rotm[2][8][4];
  __shared__ float2 M16[4][256];
  __shared__ int gtab[2][16];
  __shared__ int ftab[2][16];
  __shared__ float2 pab[2][2][16][4];
  __shared__ float2 Ahs[2][4][16][4];
  __shared__ float2 Bhs[2][4][16][4];
  __shared__ float2 Qa[2][16][16];
  __shared__ float2 Qb[2][16][16];
  __shared__ float2 SQa[2][16];
  __shared__ float2 SQb[2][4][16];
  __shared__ float dmv[2][4];
  __shared__ float xv[128];
  __shared__ float hv[32];

  const int t = threadIdx.x, b = blockIdx.x;
  const float W_MUL = 0.6324555320336759f; // sqrt(2/5)

  int* c0 = ws;
  int* c1 = ws + 1;
  float* gram_g = (float*)(ws + 4);
  unsigned* part16 = (unsigned*)(ws + 516);

  // ---- weight prefetch ----
  const float4* f1w4 = (const float4*)f1w;
  float4 rw0 = f1w4[(t << 2) + 0];
  float4 rw1 = f1w4[(t << 2) + 1];
  float4 rw2 = f1w4[(t << 2) + 2];
  float4 rw3 = f1w4[(t << 2) + 3];
  wconv[0][t] = dw1[t];
  wconv[1][t] = tw1[t];
  if (t < 72) { sw2[0][t] = dw2[t]; sw2[1][t] = tw2[t]; }
  else if (t < 80) {
    const int br = (t - 72) >> 2, i = t & 3;
    sb1[br][i] = br ? tb1[i] : db1[i];
    sb2[br][i] = br ? tb2[i] : db2[i];
  } else if (t >= 128 && t < 176) smw[t - 128] = mw[t - 128];
  else if (t >= 192 && t < 224) sf2w[t - 192] = f2w[t - 192];
  else if (t >= 224) sf1b[t - 224] = f1b[t - 224];
  if (t == 100) sf2b[0] = f2b[0];

  // ================= P1: histogram =================
  for (int i = t; i < VOC; i += 256) h[i] = 0;
  __syncthreads();
  {
    const int* __restrict__ src = (b < 64) ? (drug + (b << 12))
                                           : (target + ((b - 64) << 12));
    const int4* __restrict__ s4 = (const int4*)src;
#pragma unroll
    for (int i = 0; i < 4; ++i) {
      int4 v = s4[i * 256 + t];
      atomicAdd(&h[v.x], 1);
      atomicAdd(&h[v.y], 1);
      atomicAdd(&h[v.z], 1);
      atomicAdd(&h[v.w], 1);
    }
  }
  __syncthreads();
  {
    unsigned* __restrict__ dst = part16 + b * 5000;
    for (int i = t; i < 5000; i += 256)
      dst[i] = ((unsigned)h[2 * i] & 0xffffu) | ((unsigned)h[2 * i + 1] << 16);
  }

  // ---- hoisted (overlap the spin): E slice stage, rotm, CNOT tables ----
  const int br = (b >= 96) ? 1 : 0;
  const int start = (br ? (b - 96) : b) * 106;   // even
  const int n = (start < VOC) ? ((VOC - start < 106) ? (VOC - start) : 106) : 0;
  if (n > 0) {
    const float* __restrict__ E = br ? Et : Ed;
    const float4* __restrict__ E4 = (const float4*)(E + start * 16);
    for (int e = t; e < n * 4; e += 256) ((float4*)se)[e] = E4[e];
  }
  if (t >= 64 && t < 80) {
    // Rz @ Ry @ Rx per (layer, qubit) — depends only on mw (staged, synced)
    const int idx = t - 64, l = idx >> 3, q = idx & 7;
    float hx = 0.5f * W_MUL * smw[q * 6 + l * 3 + 0];
    float hy = 0.5f * W_MUL * smw[q * 6 + l * 3 + 1];
    float hz = 0.5f * W_MUL * smw[q * 6 + l * 3 + 2];
    float cx = cosf(hx), sx = sinf(hx);
    float cy = cosf(hy), sy = sinf(hy);
    float cz = cosf(hz), sz = sinf(hz);
    float2 m00 = make_float2(cy * cx, sy * sx);
    float2 m01 = make_float2(-sy * cx, -cy * sx);
    float2 m10 = make_float2(sy * cx, -cy * sx);
    float2 m11 = make_float2(cy * cx, -sy * sx);
    float2 e0 = make_float2(cz, -sz), e1 = make_float2(cz, sz);
    rotm[l][q][0] = cmul(e0, m00);
    rotm[l][q][1] = cmul(e0, m01);
    rotm[l][q][2] = cmul(e1, m10);
    rotm[l][q][3] = cmul(e1, m11);
  } else if (t >= 96 && t < 160) {
    // CNOT-ring bits: p0 = b1^..^b7 ; pq = b0^..^bq (q>=1)
    const int idx = t - 96;
    const int which = idx >> 5, par = (idx >> 4) & 1, nib = idx & 15;
    int b0 = (nib >> 3) & 1, b1 = (nib >> 2) & 1, b2 = (nib >> 1) & 1, b3 = nib & 1;
    if (which == 0) { // g(jh, eps)
      int p0 = b1 ^ b2 ^ b3 ^ par;
      int p1 = b0 ^ b1, p2 = p1 ^ b2, p3 = p2 ^ b3;
      gtab[par][nib] = (p0 << 3) | (p1 << 2) | (p2 << 1) | p3;
    } else {          // f(delta, jl)
      int p4 = par ^ b0, p5 = p4 ^ b1, p6 = p5 ^ b2, p7 = p6 ^ b3;
      ftab[par][nib] = (p4 << 3) | (p5 << 2) | (p6 << 1) | p7;
    }
  }

  // ================= B1: lean spin barrier =================
  __syncthreads();   // all waves' flush stores drained to L2
  if (t == 0) {
    __threadfence(); // write back this XCD's dirty part16 lines to LLC
    __hip_atomic_fetch_add(c0, 1, __ATOMIC_RELEASE, __HIP_MEMORY_SCOPE_AGENT);
    while (__hip_atomic_load(c0, __ATOMIC_RELAXED, __HIP_MEMORY_SCOPE_AGENT) < NBLK)
      __builtin_amdgcn_s_sleep(4);
  }
  __syncthreads();

  // ================= P2: count-sum -> gram =================
  if (t < 53 && 2 * t < n) {
    const int gp = (start >> 1) + t;
    const unsigned* __restrict__ P = part16 + (br ? 64 * 5000 : 0) + gp;
    const int NP = br ? 128 : 64;
    unsigned cA = 0, cB = 0;
#pragma unroll 16
    for (int bb = 0; bb < NP; ++bb) {
      unsigned w = P[bb * 5000];
      cA += w & 0xffffu;
      cB += w >> 16;
    }
    const int v0 = start + 2 * t;
    scnt[2 * t] = (v0 == 0) ? 0.f : (float)cA;
    scnt[2 * t + 1] = (float)cB;
  }
  __syncthreads();

  // M16 build (all blocks; only last block's copy consumed)
#pragma unroll
  for (int mat = 0; mat < 4; ++mat) {
    const int r = t >> 4, c = t & 15;
    const int l = mat >> 1, qb = (mat & 1) << 2;
    float2 prod = rotm[l][qb + 0][(((r >> 3) & 1) << 1) | ((c >> 3) & 1)];
    prod = cmul(prod, rotm[l][qb + 1][(((r >> 2) & 1) << 1) | ((c >> 2) & 1)]);
    prod = cmul(prod, rotm[l][qb + 2][(((r >> 1) & 1) << 1) | ((c >> 1) & 1)]);
    prod = cmul(prod, rotm[l][qb + 3][((r & 1) << 1) | (c & 1)]);
    M16[mat][t] = prod;
  }

  if (n > 0) {
    const int a = t >> 4, col = t & 15;
    float acc = 0.f;
    for (int r = 0; r < n; ++r)
      acc = fmaf(scnt[r] * se[(r << 4) + a], se[(r << 4) + col], acc);
    atomicAdd(&gram_g[(br << 8) + t], acc);
  }

  // ================= B2: arrival; last block runs tail =================
  asm volatile("s_waitcnt vmcnt(0)" ::: "memory");
  __syncthreads();
  if (t == 0) islast = (atomicAdd(c1, 1) == NBLK - 1);
  __syncthreads();
  if (!islast) return;

  sgram[t] = __hip_atomic_load(&gram_g[t], __ATOMIC_RELAXED,
                               __HIP_MEMORY_SCOPE_AGENT);
  sgram[t + 256] = __hip_atomic_load(&gram_g[t + 256], __ATOMIC_RELAXED,
                                     __HIP_MEMORY_SCOPE_AGENT);
  __syncthreads();

  // ---- conv1 -> c (4x16) per branch ----
  if (t < 128) {
    const int brx = t >> 6, o = (t >> 4) & 3, p = t & 15;
    float s = sb1[brx][o];
    const float* g = &sgram[brx << 8];
    const float* w = wconv[brx];
    for (int i = 0; i < 16; ++i) {
#pragma unroll
      for (int k = 0; k < 4; ++k) {
        int q = p + k - 1;
        if (q >= 0 && q < 16) s = fmaf(w[(o << 6) + (i << 2) + k], g[(i << 4) + q], s);
      }
    }
    cmat[brx][o][p] = s;
  }
  __syncthreads();

  // ---- Hmat (t<32) ; pab = {A,B} x {Gd,Gt} (all) ----
  if (t < 32) {
    const int brx = t >> 4, a = (t >> 2) & 3, bb = t & 3;
    float s = 0.f;
#pragma unroll
    for (int p = 0; p < 16; ++p) s = fmaf(cmat[brx][a][p], cmat[brx][bb][p], s);
    Hmat[brx][(a << 2) + bb] = s;
  }
  {
    const int op = t >> 7, brx = (t >> 6) & 1, r = (t >> 2) & 15, ca = t & 3;
    float2 s = make_float2(0.f, 0.f);
#pragma unroll
    for (int k = 0; k < 16; ++k) {
      float gk = cmat[brx][ca][k];
      float2 m = M16[op][(r << 4) + k];
      s.x = fmaf(m.x, gk, s.x);
      s.y = fmaf(m.y, gk, s.y);
    }
    pab[op][brx][r][ca] = s;
  }
  __syncthreads();

  // ---- ssum (t<2) ; parity-split halves (all) ----
  if (t < 2) {
    float s = 0.f;
#pragma unroll
    for (int i = 0; i < 16; ++i) s = fmaf(Hmat[t][i], Hmat[t][i], s);
    ssum[t] = s;
  }
#pragma unroll
  for (int e0 = 0; e0 < 4; ++e0) {
    const int e = t + (e0 << 8);
    const int isB = e >> 9, rest = e & 511;
    const int ord = rest >> 8, s = (rest >> 6) & 3, row = (rest >> 2) & 15, cc = rest & 3;
    const int delta = s >> 1, eps = s & 1;
    float2 acc = make_float2(0.f, 0.f);
    if (!isB) {
      const int br1 = ord;
      for (int jh = 0; jh < 16; ++jh) {
        if ((__popc(jh) & 1) != delta) continue;
        acc = cadd(acc, cmul(M16[2][(row << 4) + gtab[eps][jh]], pab[0][br1][jh][cc]));
      }
      Ahs[ord][s][row][cc] = acc;
    } else {
      const int br2 = ord ^ 1;
      for (int jl = 0; jl < 16; ++jl) {
        if ((__popc(jl) & 1) != eps) continue;
        acc = cadd(acc, cmul(M16[3][(row << 4) + ftab[delta][jl]], pab[1][br2][jl][cc]));
      }
      Bhs[ord][s][row][cc] = acc;
    }
  }
  __syncthreads();

  // ---- Qa/Qb quadratic forms ----
#pragma unroll
  for (int e0 = 0; e0 < 4; ++e0) {
    const int e = t + (e0 << 8);
    const int isb = e >> 9, rest = e & 511;
    const int ord = rest >> 8, ss = (rest >> 4) & 15, row = rest & 15;
    const int s = ss >> 2, sp = ss & 3;
    float2 u[4], w[4];
    const float* Hx;
    if (!isb) {
      Hx = Hmat[ord];
#pragma unroll
      for (int k = 0; k < 4; ++k) { u[k] = Ahs[ord][s][row][k]; w[k] = Ahs[ord][sp][row][k]; }
    } else {
      Hx = Hmat[ord ^ 1];
#pragma unroll
      for (int k = 0; k < 4; ++k) { u[k] = Bhs[ord][s][row][k]; w[k] = Bhs[ord][sp][row][k]; }
    }
    float2 acc = make_float2(0.f, 0.f);
#pragma unroll
    for (int a = 0; a < 4; ++a)
#pragma unroll
      for (int bb = 0; bb < 4; ++bb) {
        float2 v = cmulj(u[a], w[bb]);
        float hh = Hx[(a << 2) + bb];
        acc.x = fmaf(hh, v.x, acc.x);
        acc.y = fmaf(hh, v.y, acc.y);
      }
    if (!isb) Qa[ord][ss][row] = acc;
    else      Qb[ord][ss][row] = acc;
  }
  __syncthreads();

  // ---- SQa / SQb ----
  if (t < 32) {
    const int ord = t >> 4, ss = t & 15;
    float2 acc = make_float2(0.f, 0.f);
#pragma unroll
    for (int r = 0; r < 16; ++r) acc = cadd(acc, Qa[ord][ss][r]);
    SQa[ord][ss] = acc;
  } else if (t >= 128) {
    const int idx = t - 128;
    const int ord = idx >> 6, i = (idx >> 4) & 3, ss = idx & 15;
    float2 acc = make_float2(0.f, 0.f);
#pragma unroll
    for (int ml = 0; ml < 16; ++ml) {
      float sg = ((ml >> (3 - i)) & 1) ? -1.f : 1.f;
      float2 q = Qb[ord][ss][ml];
      acc.x = fmaf(sg, q.x, acc.x);
      acc.y = fmaf(sg, q.y, acc.y);
    }
    SQb[ord][i][ss] = acc;
  }
  __syncthreads();

  // ---- d_m / t_m ----
  if (t < 8) {
    const int ord = t >> 2, i = t & 3;
    float acc = 0.f;
#pragma unroll
    for (int ss = 0; ss < 16; ++ss) {
      float2 a = SQa[ord][ss], bq = SQb[ord][i][ss];
      acc += a.x * bq.x - a.y * bq.y;
    }
    dmv[ord][i] = acc / (ssum[0] * ssum[1]);
  }
  __syncthreads();

  // ---- conv2 3x3 pad1 -> xv[128] ----
  if (t < 128) {
    const int brx = t >> 6, idx = t & 63;
    const int o = idx >> 4, yy = (idx >> 2) & 3, xx = idx & 3;
    float s = sb2[brx][o];
    for (int ch = 0; ch < 2; ++ch)
      for (int ky = 0; ky < 3; ++ky)
        for (int kx = 0; kx < 3; ++kx) {
          int iy = yy + ky - 1, ix = xx + kx - 1;
          if (iy < 0 || iy > 3 || ix < 0 || ix > 3) continue;
          float inv = (ch == 0) ? Hmat[brx][(iy << 2) + ix] : dmv[brx][iy] * dmv[brx][ix];
          s = fmaf(sw2[brx][o * 18 + ch * 9 + ky * 3 + kx], inv, s);
        }
    xv[(brx << 6) + idx] = s;
  }
  __syncthreads();

  // ---- fc1 via register-held f1w + 8-lane shfl tree ----
  {
    const int o = t >> 3, p = t & 7;
    const float* xp = &xv[p << 4];
    float s = 0.f;
    s = fmaf(rw0.x, xp[0], s);  s = fmaf(rw0.y, xp[1], s);
    s = fmaf(rw0.z, xp[2], s);  s = fmaf(rw0.w, xp[3], s);
    s = fmaf(rw1.x, xp[4], s);  s = fmaf(rw1.y, xp[5], s);
    s = fmaf(rw1.z, xp[6], s);  s = fmaf(rw1.w, xp[7], s);
    s = fmaf(rw2.x, xp[8], s);  s = fmaf(rw2.y, xp[9], s);
    s = fmaf(rw2.z, xp[10], s); s = fmaf(rw2.w, xp[11], s);
    s = fmaf(rw3.x, xp[12], s); s = fmaf(rw3.y, xp[13], s);
    s = fmaf(rw3.z, xp[14], s); s = fmaf(rw3.w, xp[15], s);
    s += __shfl_xor(s, 1);
    s += __shfl_xor(s, 2);
    s += __shfl_xor(s, 4);
    if (p == 0) {
      float v = s + sf1b[o];
      hv[o] = v > 0.f ? v : 0.01f * v;
    }
  }
  __syncthreads();

  // ---- fc2 + leaky_relu -> out ----
  if (t == 0) {
    float s = sf2b[0];
#pragma unroll
    for (int k = 0; k < 32; ++k) s = fmaf(hv[k], sf2w[k], s);
    s = s > 0.f ? s : 0.01f * s;
    out[0] = s;
  }
}

extern "C" void kernel_launch(void* const* d_in, const int* in_sizes, int n_in,
                              void* d_out, int out_size, void* d_ws, size_t ws_size,
                              hipStream_t stream) {
  const int* drug = (const int*)d_in[0];
  const int* target = (const int*)d_in[1];
  const float* embd = (const float*)d_in[2];
  const float* embt = (const float*)d_in[3];
  const float* dw1 = (const float*)d_in[4];
  const float* db1 = (const float*)d_in[5];
  const float* tw1 = (const float*)d_in[6];
  const float* tb1 = (const float*)d_in[7];
  const float* dw2 = (const float*)d_in[8];
  const float* db2 = (const float*)d_in[9];
  const float* tw2 = (const float*)d_in[10];
  const float* tb2 = (const float*)d_in[11];
  const float* mw = (const float*)d_in[12];
  const float* f1w = (const float*)d_in[13];
  const float* f1b = (const float*)d_in[14];
  const float* f2w = (const float*)d_in[15];
  const float* f2b = (const float*)d_in[16];

  // zero c0, c1, pad, gram[512] (counters MUST be zero at every replay)
  hipMemsetAsync(d_ws, 0, 2064, stream);
  fused_kernel<<<dim3(NBLK), dim3(256), 0, stream>>>(
      drug, target, embd, embt,
      dw1, db1, tw1, tb1, dw2, db2, tw2, tb2, mw,
      f1w, f1b, f2w, f2b, (float*)d_out, (int*)d_ws);
}

// Round 10
// 29.690 us; speedup vs baseline: 1.3961x; 1.3961x over previous
//
#include <hip/hip_runtime.h>

#define VOC 10000

__device__ __forceinline__ float2 cmul(float2 a, float2 b) {
  return make_float2(a.x * b.x - a.y * b.y, a.x * b.y + a.y * b.x);
}
__device__ __forceinline__ float2 cmulj(float2 a, float2 b) { // a * conj(b)
  return make_float2(a.x * b.x + a.y * b.y, a.y * b.x - a.x * b.y);
}
__device__ __forceinline__ float2 cadd(float2 a, float2 b) {
  return make_float2(a.x + b.x, a.y + b.y);
}

// ws ints: [0]=c1 arrival counter, [1..3] pad,
// [4..515] gram (2x256 float), [516..] part16 = u32[192][5000] (2 u16/word).

// ---------------------------------------------------------------------------
// Node A: 192 thin per-block hists (4096 tokens each); u16-packed partial
// flush via plain coalesced stores. Block 0 zeroes gram+counter (visible to
// node B via the node boundary). No memset node needed.
// ---------------------------------------------------------------------------
__global__ __launch_bounds__(256) void hist_kernel(
    const int* __restrict__ drug, const int* __restrict__ target,
    unsigned* __restrict__ part16, float* __restrict__ gram_g,
    int* __restrict__ counter) {
  __shared__ int h[VOC];
  const int t = threadIdx.x, b = blockIdx.x;
  for (int i = t; i < VOC; i += 256) h[i] = 0;
  if (b == 0) {
    gram_g[t] = 0.f;
    gram_g[t + 256] = 0.f;
    if (t == 0) *counter = 0;
  }
  __syncthreads();
  const int* __restrict__ src = (b < 64) ? (drug + (b << 12))
                                         : (target + ((b - 64) << 12));
  const int4* __restrict__ s4 = (const int4*)src;
#pragma unroll
  for (int i = 0; i < 4; ++i) {
    int4 v = s4[i * 256 + t];
    atomicAdd(&h[v.x], 1);
    atomicAdd(&h[v.y], 1);
    atomicAdd(&h[v.z], 1);
    atomicAdd(&h[v.w], 1);
  }
  __syncthreads();
  unsigned* __restrict__ dst = part16 + b * 5000;
  for (int i = t; i < 5000; i += 256)
    dst[i] = ((unsigned)h[2 * i] & 0xffffu) | ((unsigned)h[2 * i + 1] << 16);
}

// ---------------------------------------------------------------------------
// Node B: 128 blocks x 157-row slices. Count-sum hoisted BEFORE the first
// barrier (overlaps E-stage staging latency) and split 2 lanes/word
// (depth 32/64 per lane, shfl_xor combine, compile-time NP). Then rotm/tabs,
// M16, weighted-gram FMA -> LLC atomicAdd. Arrival via vmcnt(0)+counter;
// the 128th block runs the verified tail inline. No threadfence anywhere.
// ---------------------------------------------------------------------------
__global__ __launch_bounds__(256) void gram_tail_kernel(
    const float* __restrict__ Ed, const float* __restrict__ Et,
    const unsigned* __restrict__ part16, float* __restrict__ gram_g,
    int* __restrict__ counter,
    const float* __restrict__ dw1, const float* __restrict__ db1,
    const float* __restrict__ tw1, const float* __restrict__ tb1,
    const float* __restrict__ dw2, const float* __restrict__ db2,
    const float* __restrict__ tw2, const float* __restrict__ tb2,
    const float* __restrict__ mw,
    const float* __restrict__ f1w, const float* __restrict__ f1b,
    const float* __restrict__ f2w, const float* __restrict__ f2b,
    float* __restrict__ out) {

  __shared__ float se[157 * 16];
  __shared__ float scnt[157];
  __shared__ int islast;
  // weights
  __shared__ float wconv[2][256];
  __shared__ float sw2[2][72];
  __shared__ float sb1[2][4], sb2[2][4];
  __shared__ float smw[48];
  __shared__ float sf1b[32], sf2w[32], sf2b[1];
  // tail scratch
  __shared__ float sgram[512];
  __shared__ float cmat[2][4][16];
  __shared__ float Hmat[2][16];
  __shared__ float ssum[2];
  __shared__ float2 rotm[2][8][4];
  __shared__ float2 M16[4][256];
  __shared__ int gtab[2][16];
  __shared__ int ftab[2][16];
  __shared__ float2 pab[2][2][16][4];
  __shared__ float2 Ahs[2][4][16][4];
  __shared__ float2 Bhs[2][4][16][4];
  __shared__ float2 Qa[2][16][16];
  __shared__ float2 Qb[2][16][16];
  __shared__ float2 SQa[2][16];
  __shared__ float2 SQb[2][4][16];
  __shared__ float dmv[2][4];
  __shared__ float xv[128];
  __shared__ float hv[32];

  const int t = threadIdx.x, b = blockIdx.x;
  const float W_MUL = 0.6324555320336759f; // sqrt(2/5)

  // ---- weight prefetch ----
  const float4* f1w4 = (const float4*)f1w;
  float4 rw0 = f1w4[(t << 2) + 0];
  float4 rw1 = f1w4[(t << 2) + 1];
  float4 rw2 = f1w4[(t << 2) + 2];
  float4 rw3 = f1w4[(t << 2) + 3];
  wconv[0][t] = dw1[t];
  wconv[1][t] = tw1[t];
  if (t < 72) { sw2[0][t] = dw2[t]; sw2[1][t] = tw2[t]; }
  else if (t < 80) {
    const int br2_ = (t - 72) >> 2, i = t & 3;
    sb1[br2_][i] = br2_ ? tb1[i] : db1[i];
    sb2[br2_][i] = br2_ ? tb2[i] : db2[i];
  } else if (t >= 128 && t < 176) smw[t - 128] = mw[t - 128];
  else if (t >= 192 && t < 224) sf2w[t - 192] = f2w[t - 192];
  else if (t >= 224) sf1b[t - 224] = f1b[t - 224];
  if (t == 100) sf2b[0] = f2b[0];

  // ---- E slice stage (issue first; stores complete by sync #1) ----
  const int br = b >> 6, local = b & 63;
  const int start = local * 157;
  const int n = (VOC - start < 157) ? (VOC - start) : 157;
  {
    const float* __restrict__ E = br ? Et : Ed;
    const float4* __restrict__ E4 = (const float4*)(E + start * 16);
    for (int e = t; e < n * 4; e += 256) ((float4*)se)[e] = E4[e];
  }

  // ---- count-sum BEFORE sync #1 (latency overlaps E-stage), 2 lanes/word ---
  const int wstart = start >> 1;
  const int wn = (((start + n - 1) >> 1) - wstart) + 1;   // <= 80
  if (t < 2 * wn) {
    const int wg = wstart + (t >> 1);
    const int half = t & 1;
    const unsigned* __restrict__ P = part16 + (br ? 64 * 5000 : 0) + wg;
    unsigned cA = 0, cB = 0;
    if (br) {
      const int d0 = half << 6;          // 64 deep per lane
#pragma unroll 32
      for (int bb = d0; bb < d0 + 64; ++bb) {
        unsigned w = P[bb * 5000];
        cA += w & 0xffffu;
        cB += w >> 16;
      }
    } else {
      const int d0 = half << 5;          // 32 deep per lane
#pragma unroll 32
      for (int bb = d0; bb < d0 + 32; ++bb) {
        unsigned w = P[bb * 5000];
        cA += w & 0xffffu;
        cB += w >> 16;
      }
    }
    cA += __shfl_xor(cA, 1);
    cB += __shfl_xor(cB, 1);
    if (half == 0) {
      const int vA = wg << 1, vB = vA | 1;
      if (vA >= start && vA < start + n) scnt[vA - start] = (vA == 0) ? 0.f : (float)cA;
      if (vB >= start && vB < start + n) scnt[vB - start] = (float)cB;
    }
  }
  __syncthreads();   // se, scnt, smw all settled

  // ---- rotm [160,176) ; CNOT tables [176,240) ----
  if (t >= 160 && t < 176) {
    const int idx = t - 160, l = idx >> 3, q = idx & 7;
    float hx = 0.5f * W_MUL * smw[q * 6 + l * 3 + 0];
    float hy = 0.5f * W_MUL * smw[q * 6 + l * 3 + 1];
    float hz = 0.5f * W_MUL * smw[q * 6 + l * 3 + 2];
    float cx = cosf(hx), sx = sinf(hx);
    float cy = cosf(hy), sy = sinf(hy);
    float cz = cosf(hz), sz = sinf(hz);
    float2 m00 = make_float2(cy * cx, sy * sx);
    float2 m01 = make_float2(-sy * cx, -cy * sx);
    float2 m10 = make_float2(sy * cx, -cy * sx);
    float2 m11 = make_float2(cy * cx, -sy * sx);
    float2 e0 = make_float2(cz, -sz), e1 = make_float2(cz, sz);
    rotm[l][q][0] = cmul(e0, m00);
    rotm[l][q][1] = cmul(e0, m01);
    rotm[l][q][2] = cmul(e1, m10);
    rotm[l][q][3] = cmul(e1, m11);
  } else if (t >= 176 && t < 240) {
    // CNOT-ring bits: p0 = b1^..^b7 ; pq = b0^..^bq (q>=1)
    const int idx = t - 176;
    const int which = idx >> 5, par = (idx >> 4) & 1, nib = idx & 15;
    int b0 = (nib >> 3) & 1, b1 = (nib >> 2) & 1, b2 = (nib >> 1) & 1, b3 = nib & 1;
    if (which == 0) { // g(jh, eps)
      int p0 = b1 ^ b2 ^ b3 ^ par;
      int p1 = b0 ^ b1, p2 = p1 ^ b2, p3 = p2 ^ b3;
      gtab[par][nib] = (p0 << 3) | (p1 << 2) | (p2 << 1) | p3;
    } else {          // f(delta, jl)
      int p4 = par ^ b0, p5 = p4 ^ b1, p6 = p5 ^ b2, p7 = p6 ^ b3;
      ftab[par][nib] = (p4 << 3) | (p5 << 2) | (p6 << 1) | p7;
    }
  }
  __syncthreads();

  // ---- M16 build (all blocks; only last block's copy consumed) ----
#pragma unroll
  for (int mat = 0; mat < 4; ++mat) {
    const int r = t >> 4, c = t & 15;
    const int l = mat >> 1, qb = (mat & 1) << 2;
    float2 prod = rotm[l][qb + 0][(((r >> 3) & 1) << 1) | ((c >> 3) & 1)];
    prod = cmul(prod, rotm[l][qb + 1][(((r >> 2) & 1) << 1) | ((c >> 2) & 1)]);
    prod = cmul(prod, rotm[l][qb + 2][(((r >> 1) & 1) << 1) | ((c >> 1) & 1)]);
    prod = cmul(prod, rotm[l][qb + 3][((r & 1) << 1) | (c & 1)]);
    M16[mat][t] = prod;
  }

  // ---- gram FMA + LLC atomic accumulate ----
  {
    const int a = t >> 4, col = t & 15;
    float acc = 0.f;
    for (int r = 0; r < n; ++r)
      acc = fmaf(scnt[r] * se[(r << 4) + a], se[(r << 4) + col], acc);
    atomicAdd(&gram_g[(br << 8) + t], acc);
  }

  // ---- arrival (own atomics acked via vmcnt; no threadfence) ----
  asm volatile("s_waitcnt vmcnt(0)" ::: "memory");
  __syncthreads();
  if (t == 0) islast = (atomicAdd(counter, 1) == 127);
  __syncthreads();
  if (!islast) return;

  sgram[t] = __hip_atomic_load(&gram_g[t], __ATOMIC_RELAXED,
                               __HIP_MEMORY_SCOPE_AGENT);
  sgram[t + 256] = __hip_atomic_load(&gram_g[t + 256], __ATOMIC_RELAXED,
                                     __HIP_MEMORY_SCOPE_AGENT);
  __syncthreads();

  // ---- conv1 -> c (4x16) per branch ----
  if (t < 128) {
    const int brx = t >> 6, o = (t >> 4) & 3, p = t & 15;
    float s = sb1[brx][o];
    const float* g = &sgram[brx << 8];
    const float* w = wconv[brx];
    for (int i = 0; i < 16; ++i) {
#pragma unroll
      for (int k = 0; k < 4; ++k) {
        int q = p + k - 1;
        if (q >= 0 && q < 16) s = fmaf(w[(o << 6) + (i << 2) + k], g[(i << 4) + q], s);
      }
    }
    cmat[brx][o][p] = s;
  }
  __syncthreads();

  // ---- Hmat (t<32) ; pab = {A,B} x {Gd,Gt} (all) ----
  if (t < 32) {
    const int brx = t >> 4, a = (t >> 2) & 3, bb = t & 3;
    float s = 0.f;
#pragma unroll
    for (int p = 0; p < 16; ++p) s = fmaf(cmat[brx][a][p], cmat[brx][bb][p], s);
    Hmat[brx][(a << 2) + bb] = s;
  }
  {
    const int op = t >> 7, brx = (t >> 6) & 1, r = (t >> 2) & 15, ca = t & 3;
    float2 s = make_float2(0.f, 0.f);
#pragma unroll
    for (int k = 0; k < 16; ++k) {
      float gk = cmat[brx][ca][k];
      float2 m = M16[op][(r << 4) + k];
      s.x = fmaf(m.x, gk, s.x);
      s.y = fmaf(m.y, gk, s.y);
    }
    pab[op][brx][r][ca] = s;
  }
  __syncthreads();

  // ---- ssum (t<2) ; parity-split halves (all) ----
  if (t < 2) {
    float s = 0.f;
#pragma unroll
    for (int i = 0; i < 16; ++i) s = fmaf(Hmat[t][i], Hmat[t][i], s);
    ssum[t] = s;
  }
#pragma unroll
  for (int e0 = 0; e0 < 4; ++e0) {
    const int e = t + (e0 << 8);
    const int isB = e >> 9, rest = e & 511;
    const int ord = rest >> 8, s = (rest >> 6) & 3, row = (rest >> 2) & 15, cc = rest & 3;
    const int delta = s >> 1, eps = s & 1;
    float2 acc = make_float2(0.f, 0.f);
    if (!isB) {
      const int br1 = ord;
      for (int jh = 0; jh < 16; ++jh) {
        if ((__popc(jh) & 1) != delta) continue;
        acc = cadd(acc, cmul(M16[2][(row << 4) + gtab[eps][jh]], pab[0][br1][jh][cc]));
      }
      Ahs[ord][s][row][cc] = acc;
    } else {
      const int br2 = ord ^ 1;
      for (int jl = 0; jl < 16; ++jl) {
        if ((__popc(jl) & 1) != eps) continue;
        acc = cadd(acc, cmul(M16[3][(row << 4) + ftab[delta][jl]], pab[1][br2][jl][cc]));
      }
      Bhs[ord][s][row][cc] = acc;
    }
  }
  __syncthreads();

  // ---- Qa/Qb quadratic forms ----
#pragma unroll
  for (int e0 = 0; e0 < 4; ++e0) {
    const int e = t + (e0 << 8);
    const int isb = e >> 9, rest = e & 511;
    const int ord = rest >> 8, ss = (rest >> 4) & 15, row = rest & 15;
    const int s = ss >> 2, sp = ss & 3;
    float2 u[4], w[4];
    const float* Hx;
    if (!isb) {
      Hx = Hmat[ord];
#pragma unroll
      for (int k = 0; k < 4; ++k) { u[k] = Ahs[ord][s][row][k]; w[k] = Ahs[ord][sp][row][k]; }
    } else {
      Hx = Hmat[ord ^ 1];
#pragma unroll
      for (int k = 0; k < 4; ++k) { u[k] = Bhs[ord][s][row][k]; w[k] = Bhs[ord][sp][row][k]; }
    }
    float2 acc = make_float2(0.f, 0.f);
#pragma unroll
    for (int a = 0; a < 4; ++a)
#pragma unroll
      for (int bb = 0; bb < 4; ++bb) {
        float2 v = cmulj(u[a], w[bb]);
        float hh = Hx[(a << 2) + bb];
        acc.x = fmaf(hh, v.x, acc.x);
        acc.y = fmaf(hh, v.y, acc.y);
      }
    if (!isb) Qa[ord][ss][row] = acc;
    else      Qb[ord][ss][row] = acc;
  }
  __syncthreads();

  // ---- SQa / SQb ----
  if (t < 32) {
    const int ord = t >> 4, ss = t & 15;
    float2 acc = make_float2(0.f, 0.f);
#pragma unroll
    for (int r = 0; r < 16; ++r) acc = cadd(acc, Qa[ord][ss][r]);
    SQa[ord][ss] = acc;
  } else if (t >= 128) {
    const int idx = t - 128;
    const int ord = idx >> 6, i = (idx >> 4) & 3, ss = idx & 15;
    float2 acc = make_float2(0.f, 0.f);
#pragma unroll
    for (int ml = 0; ml < 16; ++ml) {
      float sg = ((ml >> (3 - i)) & 1) ? -1.f : 1.f;
      float2 q = Qb[ord][ss][ml];
      acc.x = fmaf(sg, q.x, acc.x);
      acc.y = fmaf(sg, q.y, acc.y);
    }
    SQb[ord][i][ss] = acc;
  }
  __syncthreads();

  // ---- d_m / t_m ----
  if (t < 8) {
    const int ord = t >> 2, i = t & 3;
    float acc = 0.f;
#pragma unroll
    for (int ss = 0; ss < 16; ++ss) {
      float2 a = SQa[ord][ss], bq = SQb[ord][i][ss];
      acc += a.x * bq.x - a.y * bq.y;
    }
    dmv[ord][i] = acc / (ssum[0] * ssum[1]);
  }
  __syncthreads();

  // ---- conv2 3x3 pad1 -> xv[128] ----
  if (t < 128) {
    const int brx = t >> 6, idx = t & 63;
    const int o = idx >> 4, yy = (idx >> 2) & 3, xx = idx & 3;
    float s = sb2[brx][o];
    for (int ch = 0; ch < 2; ++ch)
      for (int ky = 0; ky < 3; ++ky)
        for (int kx = 0; kx < 3; ++kx) {
          int iy = yy + ky - 1, ix = xx + kx - 1;
          if (iy < 0 || iy > 3 || ix < 0 || ix > 3) continue;
          float inv = (ch == 0) ? Hmat[brx][(iy << 2) + ix] : dmv[brx][iy] * dmv[brx][ix];
          s = fmaf(sw2[brx][o * 18 + ch * 9 + ky * 3 + kx], inv, s);
        }
    xv[(brx << 6) + idx] = s;
  }
  __syncthreads();

  // ---- fc1 via register-held f1w + 8-lane shfl tree ----
  {
    const int o = t >> 3, p = t & 7;
    const float* xp = &xv[p << 4];
    float s = 0.f;
    s = fmaf(rw0.x, xp[0], s);  s = fmaf(rw0.y, xp[1], s);
    s = fmaf(rw0.z, xp[2], s);  s = fmaf(rw0.w, xp[3], s);
    s = fmaf(rw1.x, xp[4], s);  s = fmaf(rw1.y, xp[5], s);
    s = fmaf(rw1.z, xp[6], s);  s = fmaf(rw1.w, xp[7], s);
    s = fmaf(rw2.x, xp[8], s);  s = fmaf(rw2.y, xp[9], s);
    s = fmaf(rw2.z, xp[10], s); s = fmaf(rw2.w, xp[11], s);
    s = fmaf(rw3.x, xp[12], s); s = fmaf(rw3.y, xp[13], s);
    s = fmaf(rw3.z, xp[14], s); s = fmaf(rw3.w, xp[15], s);
    s += __shfl_xor(s, 1);
    s += __shfl_xor(s, 2);
    s += __shfl_xor(s, 4);
    if (p == 0) {
      float v = s + sf1b[o];
      hv[o] = v > 0.f ? v : 0.01f * v;
    }
  }
  __syncthreads();

  // ---- fc2 + leaky_relu -> out ----
  if (t == 0) {
    float s = sf2b[0];
#pragma unroll
    for (int k = 0; k < 32; ++k) s = fmaf(hv[k], sf2w[k], s);
    s = s > 0.f ? s : 0.01f * s;
    out[0] = s;
  }
}

extern "C" void kernel_launch(void* const* d_in, const int* in_sizes, int n_in,
                              void* d_out, int out_size, void* d_ws, size_t ws_size,
                              hipStream_t stream) {
  const int* drug = (const int*)d_in[0];
  const int* target = (const int*)d_in[1];
  const float* embd = (const float*)d_in[2];
  const float* embt = (const float*)d_in[3];
  const float* dw1 = (const float*)d_in[4];
  const float* db1 = (const float*)d_in[5];
  const float* tw1 = (const float*)d_in[6];
  const float* tb1 = (const float*)d_in[7];
  const float* dw2 = (const float*)d_in[8];
  const float* db2 = (const float*)d_in[9];
  const float* tw2 = (const float*)d_in[10];
  const float* tb2 = (const float*)d_in[11];
  const float* mw = (const float*)d_in[12];
  const float* f1w = (const float*)d_in[13];
  const float* f1b = (const float*)d_in[14];
  const float* f2w = (const float*)d_in[15];
  const float* f2b = (const float*)d_in[16];

  int* ws = (int*)d_ws;
  int* counter = ws;                         // [0]
  float* gram_g = (float*)(ws + 4);          // [4..515]
  unsigned* part16 = (unsigned*)(ws + 516);  // [192][5000]

  hist_kernel<<<dim3(192), dim3(256), 0, stream>>>(drug, target, part16,
                                                   gram_g, counter);
  gram_tail_kernel<<<dim3(128), dim3(256), 0, stream>>>(
      embd, embt, part16, gram_g, counter,
      dw1, db1, tw1, tb1, dw2, db2, tw2, tb2, mw,
      f1w, f1b, f2w, f2b, (float*)d_out);
}